// Round 1
// baseline (159.788 us; speedup 1.0000x reference)
//
#include <hip/hip_runtime.h>

// Problem constants (from reference): B=32, M=32, C=1024, R=28
#define Rr 28
#define Bb 32
#define Mm 32
#define Cc 1024

#define NROWS (Bb * Cc * Rr)   // 917504, rows of F to sum (each 28 contiguous floats)
#define NCOLS (Bb * Mm * Rr)   // 28672, columns of Masks to sum (stride 28)
#define ROWBLKS (NROWS / 256)  // 3584
#define COLBLKS (NCOLS / 256)  // 112

// Fused reduction kernel:
//  blocks [0, ROWBLKS)            : row[b,c,k] = sum_j F[b,c,k,j]   (contiguous, float4 x7)
//  blocks [ROWBLKS, ROWBLKS+COLBLKS): col[b,m,r] = sum_i Mk[b,m,i,r] (stride-28, lane-coalesced)
__global__ __launch_bounds__(256) void reduce_both(
    const float* __restrict__ F, const float* __restrict__ Mk,
    float* __restrict__ rowbuf, float* __restrict__ colbuf) {
    int bid = blockIdx.x;
    if (bid < ROWBLKS) {
        int idx = bid * 256 + threadIdx.x;       // one thread per 28-float row
        // byte offset idx*112 is 16B-aligned -> safe float4
        const float4* p = (const float4*)(F + (size_t)idx * Rr);
        float s = 0.f;
#pragma unroll
        for (int q = 0; q < 7; ++q) {
            float4 v = p[q];
            s += (v.x + v.y) + (v.z + v.w);
        }
        rowbuf[idx] = s;
    } else {
        int t = (bid - ROWBLKS) * 256 + threadIdx.x;  // one thread per (b,m,r)
        int bm = t / Rr;
        int r  = t - bm * Rr;
        const float* p = Mk + (size_t)bm * (Rr * Rr) + r;
        float s = 0.f;
#pragma unroll
        for (int i = 0; i < Rr; ++i) s += p[i * Rr];
        colbuf[t] = s;
    }
}

// Batched tiny GEMM: S[b,m,c] = (1/784) * sum_r col[b,m,r] * row[b,c,r]
// grid = 32 batches x 8 c-tiles of 128. LDS staging, stride padded 28->29
// (stride-28 across 64 lanes = 8-way bank conflict; 29 is odd -> conflict-free).
#define CT 128
__global__ __launch_bounds__(256) void small_gemm(
    const float* __restrict__ colbuf, const float* __restrict__ rowbuf,
    float* __restrict__ S) {
    __shared__ float col_s[Mm * 29];
    __shared__ float row_s[CT * 29];
    const int b  = blockIdx.x >> 3;
    const int c0 = (blockIdx.x & 7) * CT;
    const int t  = threadIdx.x;

    // stage col[b] : 32*28 = 896 floats
    for (int idx = t; idx < Mm * Rr; idx += 256) {
        int m = idx / Rr, r = idx - m * Rr;
        col_s[m * 29 + r] = colbuf[(size_t)b * Mm * Rr + idx];
    }
    // stage row tile : 128*28 = 3584 floats
    for (int idx = t; idx < CT * Rr; idx += 256) {
        int cl = idx / Rr, r = idx - cl * Rr;
        row_s[cl * 29 + r] = rowbuf[((size_t)b * Cc + c0) * Rr + idx];
    }
    __syncthreads();

    const int cl = t & (CT - 1);   // c within tile (lane-consecutive -> coalesced stores)
    const int mh = t >> 7;         // 0 or 1, wave-uniform
    float rreg[Rr];
#pragma unroll
    for (int r = 0; r < Rr; ++r) rreg[r] = row_s[cl * 29 + r];

    const float inv = 1.0f / (Rr * Rr);
    for (int m = mh; m < Mm; m += 2) {
        float acc = 0.f;
#pragma unroll
        for (int r = 0; r < Rr; ++r)
            acc += col_s[m * 29 + r] * rreg[r];   // col_s read is wave-uniform broadcast (free)
        S[((size_t)b * Mm + m) * Cc + c0 + cl] = acc * inv;
    }
}

extern "C" void kernel_launch(void* const* d_in, const int* in_sizes, int n_in,
                              void* d_out, int out_size, void* d_ws, size_t ws_size,
                              hipStream_t stream) {
    const float* F  = (const float*)d_in[0];   // (B, C, R, R) fp32
    const float* Mk = (const float*)d_in[1];   // (B, M, R, R) fp32
    float* S = (float*)d_out;                  // (B, M, C) fp32

    float* rowbuf = (float*)d_ws;              // B*C*R floats = 3.67 MB
    float* colbuf = rowbuf + NROWS;            // B*M*R floats = 114 KB

    reduce_both<<<ROWBLKS + COLBLKS, 256, 0, stream>>>(F, Mk, rowbuf, colbuf);
    small_gemm<<<Bb * 8, 256, 0, stream>>>(colbuf, rowbuf, S);
}